// Round 6
// baseline (350.995 us; speedup 1.0000x reference)
//
#include <hip/hip_runtime.h>

// RubiksShift forward: out[n,c,i,j] = bilinear(x[n,c], i+sh[c], j+sw[c]),
// zero outside the map. |shift| < 1 so floor(shift) ∈ {-1, 0}.
//
// r6: persistent block per plane + double-buffered LDS pipeline (T14/T3):
// per quarter-tile: {issue next-quarter global loads -> compute current
// quarter from LDS -> ds_write next quarter -> barrier}. All global traffic
// contiguous; per-channel decode once per block; conflict-free ds_read_b128.

#define NDIM 16
#define CDIM 256
#define HDIM 112
#define WDIM 112

using f32x4 = __attribute__((ext_vector_type(4))) float;

__global__ __launch_bounds__(256) void rubiks_shift_fwd(
    const float* __restrict__ x,      // [N, C, H, W]
    const float* __restrict__ shift,  // [2, C]
    float* __restrict__ out)          // [N, C, H, W]
{
    constexpr int HW    = HDIM * WDIM;     // 12544
    constexpr int HW4   = HW / 4;          // 3136 float4 per plane
    constexpr int W4    = WDIM / 4;        // 28 float4 per row
    constexpr int QROWS = 28;              // output rows per quarter
    constexpr int SROWS = 29;              // staged source rows per quarter
    constexpr int NSTG  = SROWS * W4;      // 812 float4 staged
    constexpr int NOUT  = QROWS * W4;      // 784 float4 out per quarter

    __shared__ f32x4 lds4[2][NSTG];        // 2 x 12,992 B = 25,984 B

    const int plane = blockIdx.x;          // (n*C + c)
    const int tid   = threadIdx.x;
    const int c     = plane & (CDIM - 1);

    // ---- per-channel decode (block-uniform) ----
    const float sh  = shift[c];
    const float sw  = shift[CDIM + c];
    const float flh = floorf(sh);
    const float flw = floorf(sw);
    const float frh = sh - flh;            // [0,1)
    const float frw = sw - flw;
    const int  iflh = (int)flh;            // -1 or 0
    const bool neg  = flw < 0.0f;          // floor(sw) == -1
    const float ww1 = frw, ww0 = 1.0f - frw;
    const float wh1 = frh, wh0 = 1.0f - frh;

    const f32x4* __restrict__ src4 =
        reinterpret_cast<const f32x4*>(x) + (size_t)plane * HW4;
    f32x4* __restrict__ dst4 =
        reinterpret_cast<f32x4*>(out) + (size_t)plane * HW4;

    // Staged window start per quarter: covers all in-bounds source rows.
    int ss[4];
    #pragma unroll
    for (int q = 0; q < 4; ++q)
        ss[q] = min(max(QROWS * q + iflh, 0), HDIM - SROWS);   // [0, 83]

    // ---- prologue: stage quarter 0 into buffer 0 ----
    {
        const f32x4* s = src4 + ss[0] * W4;
        f32x4 r0 = s[tid], r1 = s[tid + 256], r2 = s[tid + 512];
        f32x4 r3; const bool t4 = tid < (NSTG - 768);          // 44
        if (t4) r3 = s[tid + 768];
        lds4[0][tid] = r0; lds4[0][tid + 256] = r1; lds4[0][tid + 512] = r2;
        if (t4) lds4[0][tid + 768] = r3;
    }
    __syncthreads();

    #pragma unroll
    for (int q = 0; q < 4; ++q) {
        // (a) issue next quarter's global loads (in flight across compute)
        f32x4 r0, r1, r2, r3;
        bool t4 = false;
        if (q < 3) {
            const f32x4* s = src4 + ss[q + 1] * W4;
            r0 = s[tid]; r1 = s[tid + 256]; r2 = s[tid + 512];
            t4 = tid < (NSTG - 768);
            if (t4) r3 = s[tid + 768];
        }

        // (b) compute quarter q from lds buffer q&1
        const f32x4* buf = lds4[q & 1];
        const int stage0 = ss[q];
        #pragma unroll
        for (int t = 0; t < 4; ++t) {
            const int m = tid + t * 256;
            if (t == 3 && m >= NOUT) break;                    // tail: 16 threads
            const int i_loc = m / W4;                          // magic-mul
            const int j4    = m - i_loc * W4;

            const int i0   = QROWS * q + i_loc + iflh;         // top source row
            const int li0  = i0 - stage0;
            const int li0c = max(li0, 0);
            const int li1c = min(li0 + 1, SROWS - 1);
            const float w0 = (i0 >= 0)       ? wh0 : 0.0f;
            const float w1 = (i0 + 1 < HDIM) ? wh1 : 0.0f;

            const int jlo  = neg ? j4 - 1 : j4;
            const int jloc = max(jlo, 0);
            const int jhic = min(jlo + 1, W4 - 1);

            const f32x4 aL = buf[li0c * W4 + jloc];
            const f32x4 aH = buf[li0c * W4 + jhic];
            const f32x4 bL = buf[li1c * W4 + jloc];
            const f32x4 bH = buf[li1c * W4 + jhic];

            float ta[5], tb[5];
            if (neg) {  // taps j-1..j+3 : {lo.w, hi.x, hi.y, hi.z, hi.w}
                ta[0]=aL[3]; ta[1]=aH[0]; ta[2]=aH[1]; ta[3]=aH[2]; ta[4]=aH[3];
                tb[0]=bL[3]; tb[1]=bH[0]; tb[2]=bH[1]; tb[3]=bH[2]; tb[4]=bH[3];
                if (j4 == 0) { ta[0] = 0.0f; tb[0] = 0.0f; }   // col -1
            } else {    // taps j..j+4 : {lo.x, lo.y, lo.z, lo.w, hi.x}
                ta[0]=aL[0]; ta[1]=aL[1]; ta[2]=aL[2]; ta[3]=aL[3]; ta[4]=aH[0];
                tb[0]=bL[0]; tb[1]=bL[1]; tb[2]=bL[2]; tb[3]=bL[3]; tb[4]=bH[0];
                if (j4 == W4 - 1) { ta[4] = 0.0f; tb[4] = 0.0f; } // col 112
            }

            f32x4 o;
            #pragma unroll
            for (int k = 0; k < 4; ++k) {
                const float ha = ww0 * ta[k] + ww1 * ta[k + 1];
                const float hb = ww0 * tb[k] + ww1 * tb[k + 1];
                o[k] = w0 * ha + w1 * hb;
            }
            __builtin_nontemporal_store(o, dst4 + q * NOUT + m);
        }

        // (c) write next quarter to the other buffer (waitcnt lands here)
        if (q < 3) {
            f32x4* nb = lds4[(q + 1) & 1];
            nb[tid] = r0; nb[tid + 256] = r1; nb[tid + 512] = r2;
            if (t4) nb[tid + 768] = r3;
        }
        __syncthreads();
    }
}

extern "C" void kernel_launch(void* const* d_in, const int* in_sizes, int n_in,
                              void* d_out, int out_size, void* d_ws, size_t ws_size,
                              hipStream_t stream) {
    const float* x     = (const float*)d_in[0];
    const float* shift = (const float*)d_in[1];
    float* out         = (float*)d_out;

    constexpr int grid = NDIM * CDIM;      // 4096 blocks, one per plane
    rubiks_shift_fwd<<<grid, 256, 0, stream>>>(x, shift, out);
}

// Round 7
// 336.284 us; speedup vs baseline: 1.0437x; 1.0437x over previous
//
#include <hip/hip_runtime.h>

// RubiksShift forward: out[n,c,i,j] = bilinear(x[n,c], i+sh[c], j+sw[c]),
// zero outside the map. |shift| < 1 so floor(shift) ∈ {-1, 0}.
//
// r7: copy-shaped streaming. No LDS, no barriers, no vmcnt(0) drains.
// Block = half-plane (8192 blocks x 256 threads). Each thread: 7 output
// float4s; per f4 and per source row: 1 ALIGNED dwordx4 at col j (works for
// both shift signs) + 1 dword at j-1 (neg) / j+4 (pos). All 28 loads issued
// up front; computes drain them with compiler-counted vmcnt; stores are NT.

#define NDIM 16
#define CDIM 256
#define HDIM 112
#define WDIM 112

using f32x4 = __attribute__((ext_vector_type(4))) float;

__global__ __launch_bounds__(256) void rubiks_shift_fwd(
    const float* __restrict__ x,      // [N, C, H, W]
    const float* __restrict__ shift,  // [2, C]
    float* __restrict__ out)          // [N, C, H, W]
{
    constexpr int HW    = HDIM * WDIM;   // 12544
    constexpr int W4    = WDIM / 4;      // 28 float4 per row
    constexpr int HALF4 = 56 * W4;       // 1568 float4 per half-plane
    constexpr int TAIL  = HALF4 - 6 * 256;  // 32 threads active in slot 6

    const int bid   = blockIdx.x;
    const int tid   = threadIdx.x;
    const int plane = bid >> 1;          // (n*C + c)
    const int half  = bid & 1;
    const int c     = plane & (CDIM - 1);

    // ---- block-uniform per-channel decode (validated in r5) ----
    const float sh  = shift[c];
    const float sw  = shift[CDIM + c];
    const float flh = floorf(sh);
    const float flw = floorf(sw);
    const float frh = sh - flh;          // [0,1)
    const float frw = sw - flw;
    const int  iflh = (int)flh;          // -1 or 0
    const bool neg  = flw < 0.0f;        // floor(sw) == -1 (block-uniform)
    const float ww1 = frw, ww0 = 1.0f - frw;
    const float wh1 = frh, wh0 = 1.0f - frh;

    const float* __restrict__ pb = x + (size_t)plane * HW;
    const int row_base = half * 56;

    // ---- per-slot (i_loc, j4), incremental: +256 f4 = +9 rows +4 cols ----
    int il[7], j4a[7];
    {
        int i_loc = tid / W4;            // const divisor -> magic mul
        int j4    = tid - i_loc * W4;
        #pragma unroll
        for (int u = 0; u < 7; ++u) {
            il[u] = i_loc; j4a[u] = j4;
            i_loc += 9; j4 += 4;
            if (j4 >= W4) { j4 -= W4; i_loc += 1; }
        }
    }

    // ---- issue all 28 loads (4 per slot), straight-line ----
    f32x4 F0[7], F1[7];
    float S0[7], S1[7];
    #pragma unroll
    for (int u = 0; u < 7; ++u) {
        const int i_loc = (u == 6) ? min(il[u], 55) : il[u];  // tail addr clamp
        const int j     = j4a[u] * 4;
        const int i0    = row_base + i_loc + iflh;
        const int i0c   = max(i0, 0);
        const int i1c   = min(i0 + 1, HDIM - 1);
        const int jm    = neg ? max(j - 1, 0) : min(j + 4, WDIM - 1);
        const float* r0 = pb + i0c * WDIM;
        const float* r1 = pb + i1c * WDIM;
        F0[u] = *reinterpret_cast<const f32x4*>(r0 + j);   // aligned (j % 4 == 0)
        F1[u] = *reinterpret_cast<const f32x4*>(r1 + j);
        S0[u] = r0[jm];                                    // L1-hit neighbor dword
        S1[u] = r1[jm];
    }

    // ---- compute + NT store; loads drain with counted vmcnt ----
    f32x4* __restrict__ dst = reinterpret_cast<f32x4*>(out)
                              + (size_t)plane * (HW / 4) + half * HALF4 + tid;
    #pragma unroll
    for (int u = 0; u < 7; ++u) {
        const int i_loc = (u == 6) ? min(il[u], 55) : il[u];
        const int j     = j4a[u] * 4;
        const int i0    = row_base + i_loc + iflh;
        const float w0  = (i0 >= 0)       ? wh0 : 0.0f;   // top row validity
        const float w1  = (i0 + 1 < HDIM) ? wh1 : 0.0f;   // bottom row validity

        float t0[5], t1[5];
        if (neg) {   // taps j-1..j+3 = {S, F.x, F.y, F.z, F.w}; mask col -1
            const bool ok0 = (j > 0);
            t0[0] = ok0 ? S0[u] : 0.0f;  t1[0] = ok0 ? S1[u] : 0.0f;
            t0[1]=F0[u][0]; t0[2]=F0[u][1]; t0[3]=F0[u][2]; t0[4]=F0[u][3];
            t1[1]=F1[u][0]; t1[2]=F1[u][1]; t1[3]=F1[u][2]; t1[4]=F1[u][3];
        } else {     // taps j..j+4 = {F.x, F.y, F.z, F.w, S}; mask col 112
            const bool ok4 = (j < WDIM - 4);
            t0[0]=F0[u][0]; t0[1]=F0[u][1]; t0[2]=F0[u][2]; t0[3]=F0[u][3];
            t1[0]=F1[u][0]; t1[1]=F1[u][1]; t1[2]=F1[u][2]; t1[3]=F1[u][3];
            t0[4] = ok4 ? S0[u] : 0.0f;  t1[4] = ok4 ? S1[u] : 0.0f;
        }

        f32x4 o;
        #pragma unroll
        for (int k = 0; k < 4; ++k) {
            const float h0 = ww0 * t0[k] + ww1 * t0[k + 1];
            const float h1 = ww0 * t1[k] + ww1 * t1[k + 1];
            o[k] = w0 * h0 + w1 * h1;
        }
        if (u < 6 || tid < TAIL)
            __builtin_nontemporal_store(o, dst + u * 256);
    }
}

extern "C" void kernel_launch(void* const* d_in, const int* in_sizes, int n_in,
                              void* d_out, int out_size, void* d_ws, size_t ws_size,
                              hipStream_t stream) {
    const float* x     = (const float*)d_in[0];
    const float* shift = (const float*)d_in[1];
    float* out         = (float*)d_out;

    constexpr int grid = NDIM * CDIM * 2;   // 8192 blocks, one per half-plane
    rubiks_shift_fwd<<<grid, 256, 0, stream>>>(x, shift, out);
}